// Round 9
// baseline (231.045 us; speedup 1.0000x reference)
//
#include <hip/hip_runtime.h>

// Problem constants
#define NB 2
#define LL 2048
#define DD 1024
#define HH 16
#define NHH (NB*HH)          // 32 (n,h) pairs
#define LT (LL/64)           // 32 tiles of 64
#define KT16 (LL/16)         // 128 16-col tiles
#define CEXP 0.0450842200277801f   // log2(e)/32 : exp(x/32) == exp2(x*CEXP)

typedef __bf16 bf16x8 __attribute__((ext_vector_type(8)));
typedef unsigned short u16x8 __attribute__((ext_vector_type(8)));
typedef float f32x4 __attribute__((ext_vector_type(4)));

#define MFMA16 __builtin_amdgcn_mfma_f32_16x16x32_bf16
#define EXP2 __builtin_amdgcn_exp2f
#define LOG2 __builtin_amdgcn_logf

__device__ __forceinline__ unsigned short f2bf(float f) {
    unsigned u = __float_as_uint(f);
    return (unsigned short)((u + 0x7fffu + ((u >> 16) & 1u)) >> 16);   // RNE
}
__device__ __forceinline__ float bf2f(unsigned short u) {
    return __uint_as_float(((unsigned)u) << 16);
}
__device__ __forceinline__ bf16x8 ldfrag(const unsigned short* p) {
    return *reinterpret_cast<const bf16x8*>(p);
}
__device__ __forceinline__ bf16x8 cvt8v(float4 a, float4 b) {
    u16x8 u;
    u[0]=f2bf(a.x); u[1]=f2bf(a.y); u[2]=f2bf(a.z); u[3]=f2bf(a.w);
    u[4]=f2bf(b.x); u[5]=f2bf(b.y); u[6]=f2bf(b.z); u[7]=f2bf(b.w);
    return __builtin_bit_cast(bf16x8, u);
}
__device__ __forceinline__ ushort4 pack4(f32x4 d, float sc) {
    ushort4 o;
    o.x = f2bf(d[0]*sc); o.y = f2bf(d[1]*sc); o.z = f2bf(d[2]*sc); o.w = f2bf(d[3]*sc);
    return o;
}
// async global->LDS, 16B per lane; LDS dest must be linear (base + lane*16)
__device__ __forceinline__ void gload16(const unsigned short* g, unsigned short* l) {
    __builtin_amdgcn_global_load_lds(
        (const __attribute__((address_space(1))) unsigned int*)g,
        (__attribute__((address_space(3))) unsigned int*)l, 16, 0, 0);
}

// ---------------------------------------------------------------------------
// K0a (prepM): M^T frags for proj.  E = q Wq^T Wk ok^T = query . M . okeys^T,
// M = Wq^T Wk.  A-frag content: Mt[o][k] = M[k][o] = sum_i Wq[i][k]*Wk[i][o],
// slot s = f*64+lane (f = mt*2+half), o = mt*16+(lane&15),
// k = (lane>>4)*8 + half*32 + e.  262K MAC total, 16 blocks.
// ---------------------------------------------------------------------------
__global__ __launch_bounds__(256) void prepM_kernel(
    const float* __restrict__ Wq, const float* __restrict__ Wk,
    unsigned short* __restrict__ wfrag)
{
    __shared__ float WqL[64 * 68];
    __shared__ float WkL[64 * 68];
    const int t = threadIdx.x;
    // stage (padded rows, stride 68)
#pragma unroll
    for (int j = 0; j < 4; ++j) {
        const int p = t * 16 + j * 4;           // 0..4095, col multiple of 4
        const int r = p >> 6, c = p & 63;
        *reinterpret_cast<float4*>(&WqL[r * 68 + c]) =
            *reinterpret_cast<const float4*>(Wq + p);
        *reinterpret_cast<float4*>(&WkL[r * 68 + c]) =
            *reinterpret_cast<const float4*>(Wk + p);
    }
    __syncthreads();
    const int s = blockIdx.x * 32 + (t >> 3);   // 0..511
    const int e = t & 7;
    const int f = s >> 6, lane = s & 63;
    const int mt = f >> 1, half = f & 1;
    const int o = mt * 16 + (lane & 15);
    const int k = (lane >> 4) * 8 + half * 32 + e;
    float acc = 0.f;
#pragma unroll 8
    for (int i = 0; i < 64; ++i)
        acc += WqL[i * 68 + k] * WkL[i * 68 + o];
    wfrag[(size_t)s * 8 + e] = f2bf(acc);
}

// ---------------------------------------------------------------------------
// K0b (prep2): W2T = fc . blockdiag(Wv): diag_s/colsum are scalar per (l,h)
// row, so the Wv projection commutes with them and folds into fc:
// out = X @ W2T^T with X = ds*values + cs*ovals (raw fp32 inputs),
// W2T[j][64h+d] = sum_i fc[j][64h+i] * Wv[i][d].  Stored bf16 in fcwb's
// [j][k] layout (drop-in B for out_kernel).  1024 blocks (one j-row each).
// ---------------------------------------------------------------------------
__global__ __launch_bounds__(256) void prep2_kernel(
    const float* __restrict__ fc_w, const float* __restrict__ Wv,
    unsigned short* __restrict__ fcwb)
{
    __shared__ float wvL[64 * 64];      // Wv[i][d], linear (reads are spread)
    __shared__ float fcL[16 * 68];      // fc row, padded per head
    const int j = blockIdx.x;
    const int t = threadIdx.x;
#pragma unroll
    for (int q = 0; q < 4; ++q)
        reinterpret_cast<float4*>(wvL)[t * 4 + q] =
            reinterpret_cast<const float4*>(Wv)[t * 4 + q];
    {
        const int p = t * 4;                    // 0..1023
        const float4 v = *reinterpret_cast<const float4*>(fc_w + (size_t)j * DD + p);
        *reinterpret_cast<float4*>(&fcL[(p >> 6) * 68 + (p & 63)]) = v;
    }
    __syncthreads();
    const int h = t >> 4, db = (t & 15) * 4;
    float a0 = 0.f, a1 = 0.f, a2 = 0.f, a3 = 0.f;
#pragma unroll 8
    for (int i = 0; i < 64; ++i) {
        const float fv = fcL[h * 68 + i];
        const float4 wv4 = *reinterpret_cast<const float4*>(&wvL[i * 64 + db]);
        a0 += fv * wv4.x; a1 += fv * wv4.y; a2 += fv * wv4.z; a3 += fv * wv4.w;
    }
    ushort4 o;
    o.x = f2bf(a0); o.y = f2bf(a1); o.z = f2bf(a2); o.w = f2bf(a3);
    *reinterpret_cast<ushort4*>(fcwb + (size_t)j * DD + h * 64 + db) = o;
}

// ---------------------------------------------------------------------------
// K1: grid (64,16).  qb' = query @ M (8 MFMAs, CEXP-prescaled bf16);
// okb = cvt(okeys) RAW (no projection -- folded into M);
// ediag = (query@M) . keys via LDS bounce (C-layout qa -> B-layout read),
// keys needs no projection either.  Was 24 MFMAs + 2 W-frag sets + a whole
// z=1 pass; now 8 MFMAs + 1 frag set, 48MB read / 16MB write.
// ---------------------------------------------------------------------------
__global__ __launch_bounds__(256) void proj_kernel(
    const float* __restrict__ query, const float* __restrict__ keys,
    const float* __restrict__ okeys, const unsigned short* __restrict__ wfrag,
    unsigned short* __restrict__ qb, unsigned short* __restrict__ okb,
    float* __restrict__ ediag)
{
    __shared__ float eb[4][16][68];     // per-wave qa bounce (padded rows)
    const int t = threadIdx.x;
    const int w = t >> 6;
    const int lane = t & 63;
    const int n16 = lane & 15;
    const int quad = lane >> 4;
    const int h = blockIdx.y;
    const int row = blockIdx.x * 64 + w * 16 + n16;
    const int nn = row >> 11;
    const int ll = row & 2047;
    const size_t xoff  = (size_t)row * DD + h * 64 + quad * 8;
    const size_t qbase = (((size_t)(nn * HH + h)) * LL + ll) * 64;

    // ---- issue all loads first ----
    const float4* kp = reinterpret_cast<const float4*>(keys  + xoff);
    const float4* qp = reinterpret_cast<const float4*>(query + xoff);
    const float4* op = reinterpret_cast<const float4*>(okeys + xoff);
    float4 k0 = kp[0], k1 = kp[1], k2 = kp[8], k3 = kp[9];   // dims 8q.., 32+8q..
    float4 q0 = qp[0], q1 = qp[1], q2 = qp[8], q3 = qp[9];
    float4 o0 = op[0], o1 = op[1], o2 = op[8], o3 = op[9];
    bf16x8 wm[8];
#pragma unroll
    for (int f = 0; f < 8; ++f)
        wm[f] = ldfrag(wfrag + (size_t)(f * 64 + lane) * 8);

    // okb: raw cvt, B-layout (position == dim), 16B stores
    bf16x8 xo0 = cvt8v(o0, o1), xo1 = cvt8v(o2, o3);
    *reinterpret_cast<bf16x8*>(okb + qbase + quad * 8)      = xo0;
    *reinterpret_cast<bf16x8*>(okb + qbase + 32 + quad * 8) = xo1;

    // qb' = query @ M
    bf16x8 xq0 = cvt8v(q0, q1), xq1 = cvt8v(q2, q3);
    f32x4 qa[4];
#pragma unroll
    for (int mt = 0; mt < 4; ++mt) {
        f32x4 d = {0.f,0.f,0.f,0.f};
        d = MFMA16(wm[mt*2], xq0, d, 0,0,0);
        qa[mt] = MFMA16(wm[mt*2+1], xq1, d, 0,0,0);
        *reinterpret_cast<ushort4*>(qb + qbase + mt*16 + quad*4) = pack4(qa[mt], CEXP);
    }

    // ediag[l] = (query@M).keys : bounce qa (C-layout dims mt*16+quad*4+r)
    // through LDS, read back at this lane's keys dims (8q.., 32+8q..).
#pragma unroll
    for (int mt = 0; mt < 4; ++mt)
        *reinterpret_cast<f32x4*>(&eb[w][n16][mt*16 + quad*4]) = qa[mt];
    __syncthreads();
    const float* rp = eb[w][n16];
    const float4 a0 = *reinterpret_cast<const float4*>(&rp[quad*8]);
    const float4 a1 = *reinterpret_cast<const float4*>(&rp[quad*8 + 4]);
    const float4 a2 = *reinterpret_cast<const float4*>(&rp[32 + quad*8]);
    const float4 a3 = *reinterpret_cast<const float4*>(&rp[32 + quad*8 + 4]);
    float p = a0.x*k0.x + a0.y*k0.y + a0.z*k0.z + a0.w*k0.w
            + a1.x*k1.x + a1.y*k1.y + a1.z*k1.z + a1.w*k1.w
            + a2.x*k2.x + a2.y*k2.y + a2.z*k2.z + a2.w*k2.w
            + a3.x*k3.x + a3.y*k3.y + a3.z*k3.z + a3.w*k3.w;
    p += __shfl_xor(p, 16);
    p += __shfl_xor(p, 32);
    if (lane < 16)
        ediag[((size_t)(nn * HH + h)) * LL + ll] = p;
}

// ---------------------------------------------------------------------------
// K2: Z[q] = sum_{l<q} exp(e[q,l]/32), LDS-staged mini-GEMM (verified R5/R7
// 64-q/1024-block form -- small blocks load-balance the triangle).
// ---------------------------------------------------------------------------
__global__ __launch_bounds__(256) void zrow_part(
    const unsigned short* __restrict__ qb, const unsigned short* __restrict__ okb,
    float* __restrict__ Zbuf)
{
    __shared__ unsigned short slds[2][64 * 64];   // 2 x 8KB staged okb strips

    const int bid = blockIdx.x;       // 0..1023
    const int nh = bid & 31;
    const int qt = 31 - (bid >> 5);   // longest (32 strips) first
    const int t = threadIdx.x;
    const int w = t >> 6;
    const int lane = t & 63;
    const int n = lane & 15;
    const int quad = lane >> 4;
    const size_t base = (size_t)nh * (LL * 64);
    const size_t nhL = (size_t)nh * LL;

    // held B-frags: qb rows q = qt*64 + w*16 + n
    const unsigned short* bp = qb + base + (size_t)(qt*64 + w*16 + n) * 64 + quad * 8;
    const bf16x8 bq0 = ldfrag(bp);
    const bf16x8 bq1 = ldfrag(bp + 32);

    // staging: thread t -> strip-rows srow, srow+32; source chunk pre-swizzled
    const int srow = t >> 3;                        // 0..31
    const int schunk = (t & 7) ^ (srow & 7);        // inverse of read swizzle
    const int soff = srow * 64 + schunk * 8;
    const int nst = qt + 1;

    {   // prologue: stage strip 0 (l in [0,64))
        const unsigned short* s0 = okb + base + soff;
        gload16(s0, &slds[0][t * 8]);
        gload16(s0 + 32 * 64, &slds[0][2048 + t * 8]);
    }
    __syncthreads();

    const int rs0 = (quad ^ (n & 7)) * 8;           // swizzled read offsets
    const int rs1 = ((quad + 4) ^ (n & 7)) * 8;

    float zacc = 0.f;
    int buf = 0;
    for (int si = 0; si < nst; ++si) {
        if (si + 1 < nst) {                         // stage next strip first
            const unsigned short* s0 = okb + base + (size_t)((si + 1) * 64) * 64 + soff;
            gload16(s0, &slds[buf ^ 1][t * 8]);
            gload16(s0 + 32 * 64, &slds[buf ^ 1][2048 + t * 8]);
        }
        const unsigned short* S = &slds[buf][0];
        const bool dstrip = (si == qt);             // strip containing l == q
#pragma unroll
        for (int sub = 0; sub < 4; ++sub) {
            if (dstrip && sub > w) continue;        // l > q entirely
            const int row = sub * 16 + n;
            const bf16x8 a0 = ldfrag(S + row * 64 + rs0);
            const bf16x8 a1 = ldfrag(S + row * 64 + rs1);
            f32x4 d = {0.f, 0.f, 0.f, 0.f};
            d = MFMA16(a0, bq0, d, 0, 0, 0);
            d = MFMA16(a1, bq1, d, 0, 0, 0);
            if (dstrip && sub == w) {               // diagonal: keep l < q
#pragma unroll
                for (int r = 0; r < 4; ++r)
                    if (quad * 4 + r < n) zacc += EXP2(d[r]);
            } else {
#pragma unroll
                for (int r = 0; r < 4; ++r) zacc += EXP2(d[r]);
            }
        }
        __syncthreads();                            // next buf staged; reads done
        buf ^= 1;
    }

    zacc += __shfl_down(zacc, 32);
    zacc += __shfl_down(zacc, 16);
    if (lane < 16)
        Zbuf[nhL + qt * 64 + w * 16 + lane] = zacc;   // plain store, single owner
}

// ---------------------------------------------------------------------------
// K3: colsum[l] = sum_{q>l} exp(e[q,l]/32) / Z_full[q].  R5/R7 structure;
// lg2iz acc-init: d_init = -log2(Z+de) so exp2(d) == exp(e/32)*iz.
// ---------------------------------------------------------------------------
__global__ __launch_bounds__(256) void colsum_part(
    const unsigned short* __restrict__ qb, const unsigned short* __restrict__ okb,
    const float* __restrict__ Zbuf, const float* __restrict__ ediag,
    float* __restrict__ colsum)
{
    __shared__ unsigned short slds[2][64 * 64];   // 2 x 8KB staged qb strips
    __shared__ __align__(16) float izlds[2][64];  // lg2iz per strip

    const int bid = blockIdx.x;       // 0..1023
    const int nh = bid & 31;
    const int lt = bid >> 5;          // lt=0 (32 strips) first
    const int t = threadIdx.x;
    const int w = t >> 6;
    const int lane = t & 63;
    const int n = lane & 15;
    const int quad = lane >> 4;
    const size_t base = (size_t)nh * (LL * 64);
    const size_t nhL = (size_t)nh * LL;

    // held B-frags: okb rows l = lt*64 + w*16 + n
    const unsigned short* bp = okb + base + (size_t)(lt*64 + w*16 + n) * 64 + quad * 8;
    const bf16x8 bl0 = ldfrag(bp);
    const bf16x8 bl1 = ldfrag(bp + 32);

    const int srow = t >> 3;
    const int schunk = (t & 7) ^ (srow & 7);
    const int soff = srow * 64 + schunk * 8;
    const int nst = 32 - lt;
    const int q00 = lt * 64;                        // strip si q-base = q00+si*64

    {   // prologue: stage strip 0 + its lg2iz
        const unsigned short* s0 = qb + base + (size_t)q00 * 64 + soff;
        gload16(s0, &slds[0][t * 8]);
        gload16(s0 + 32 * 64, &slds[0][2048 + t * 8]);
        if (t < 64) {
            const float z = Zbuf[nhL + q00 + t];
            const float e = ediag[nhL + q00 + t];
            izlds[0][t] = -LOG2(z + EXP2(e * CEXP));
        }
    }
    __syncthreads();

    const int rs0 = (quad ^ (n & 7)) * 8;
    const int rs1 = ((quad + 4) ^ (n & 7)) * 8;

    float cacc = 0.f;
    int buf = 0;
    for (int si = 0; si < nst; ++si) {
        if (si + 1 < nst) {
            const int qn = q00 + (si + 1) * 64;
            const unsigned short* s0 = qb + base + (size_t)qn * 64 + soff;
            gload16(s0, &slds[buf ^ 1][t * 8]);
            gload16(s0 + 32 * 64, &slds[buf ^ 1][2048 + t * 8]);
            if (t < 64) {
                const float z = Zbuf[nhL + qn + t];
                const float e = ediag[nhL + qn + t];
                izlds[buf ^ 1][t] = -LOG2(z + EXP2(e * CEXP));
            }
        }
        const unsigned short* S = &slds[buf][0];
        const bool dstrip = (si == 0);              // strip containing q == l
#pragma unroll
        for (int sub = 0; sub < 4; ++sub) {
            if (dstrip && sub < w) continue;        // q < l entirely
            const int row = sub * 16 + n;
            const bf16x8 a0 = ldfrag(S + row * 64 + rs0);
            const bf16x8 a1 = ldfrag(S + row * 64 + rs1);
            const f32x4 lgv = *reinterpret_cast<const f32x4*>(
                &izlds[buf][sub * 16 + quad * 4]);
            f32x4 d = lgv;                          // acc init = lg2iz[q]
            d = MFMA16(a0, bl0, d, 0, 0, 0);
            d = MFMA16(a1, bl1, d, 0, 0, 0);
            if (dstrip && sub == w) {               // diagonal: keep q > l
#pragma unroll
                for (int r = 0; r < 4; ++r)
                    if (quad * 4 + r > n) cacc += EXP2(d[r]);
            } else {
#pragma unroll
                for (int r = 0; r < 4; ++r) cacc += EXP2(d[r]);
            }
        }
        __syncthreads();
        buf ^= 1;
    }

    cacc += __shfl_down(cacc, 32);
    cacc += __shfl_down(cacc, 16);
    if (lane < 16)
        colsum[nhL + lt * 64 + w * 16 + lane] = cacc;  // plain store
}

// ---------------------------------------------------------------------------
// K6: out = (ds*values + cs*ovals) @ W2T^T + fc_b -- Wv folded into W2T, so
// A-staging reads RAW fp32 values/ovals (vb/ovb and proj z=1 deleted).
// diag_s computed inline from Zbuf+ediag.
// ---------------------------------------------------------------------------
#define LOADA(v0S, v1S, o0S, o1S, zS, eS, csS, k) do {                     \
    v0S = *reinterpret_cast<const float4*>(pv  + (k)*32);                  \
    v1S = *reinterpret_cast<const float4*>(pv  + (k)*32 + 4);              \
    o0S = *reinterpret_cast<const float4*>(pov + (k)*32);                  \
    o1S = *reinterpret_cast<const float4*>(pov + (k)*32 + 4);              \
    zS  = Zbuf  [scbase + ((k)>>1)*LL];                                    \
    eS  = ediag [scbase + ((k)>>1)*LL];                                    \
    csS = colsum[scbase + ((k)>>1)*LL];                                    \
} while (0)

#define CVTWRITE(v0S, v1S, o0S, o1S, zS, eS, csS, dst) do {                \
    const float de_ = EXP2(eS * CEXP);                                     \
    const float ds_ = de_ * (1.f / (zS + de_));                            \
    u16x8 o_;                                                              \
    o_[0] = f2bf(ds_*v0S.x + csS*o0S.x);                                   \
    o_[1] = f2bf(ds_*v0S.y + csS*o0S.y);                                   \
    o_[2] = f2bf(ds_*v0S.z + csS*o0S.z);                                   \
    o_[3] = f2bf(ds_*v0S.w + csS*o0S.w);                                   \
    o_[4] = f2bf(ds_*v1S.x + csS*o1S.x);                                   \
    o_[5] = f2bf(ds_*v1S.y + csS*o1S.y);                                   \
    o_[6] = f2bf(ds_*v1S.z + csS*o1S.z);                                   \
    o_[7] = f2bf(ds_*v1S.w + csS*o1S.w);                                   \
    *reinterpret_cast<u16x8*>(dst) = o_;                                   \
} while (0)

#define COMPUTE(Abuf, Bbuf) do {                                           \
    bf16x8 af_[4], bf_[2];                                                 \
    _Pragma("unroll")                                                      \
    for (int mt = 0; mt < 4; ++mt)                                         \
        af_[mt] = ldfrag((Abuf) + (wr*64 + mt*16 + n)*32 + quad*8);        \
    _Pragma("unroll")                                                      \
    for (int nt = 0; nt < 2; ++nt)                                         \
        bf_[nt] = ldfrag((Bbuf) + (wc*32 + nt*16 + n)*32 + quad*8);        \
    _Pragma("unroll")                                                      \
    for (int mt = 0; mt < 4; ++mt)                                         \
        _Pragma("unroll")                                                  \
        for (int nt = 0; nt < 2; ++nt)                                     \
            acc[mt][nt] = MFMA16(af_[mt], bf_[nt], acc[mt][nt], 0,0,0);    \
} while (0)

__global__ __launch_bounds__(512) void out_kernel(
    const float* __restrict__ values, const float* __restrict__ ovals,
    const float* __restrict__ Zbuf, const float* __restrict__ ediag,
    const float* __restrict__ colsum,
    const unsigned short* __restrict__ fcwb, const float* __restrict__ fc_b,
    float* __restrict__ out)
{
    __shared__ unsigned short lds[2][2][128 * 32];   // [buf][A/B][row*32+k], 32 KB

    const int bid = blockIdx.x;                      // 0..255
    const int swz = (bid & 7) * 32 + (bid >> 3);     // XCD swizzle (256%8==0)
    const int ct = swz & 7;                          // col tile (128 cols)
    const int rt = swz >> 3;                         // row tile (128 rows)
    const int row0 = rt * 128, col0 = ct * 128;

    const int t = threadIdx.x;
    const int w = t >> 6, lane = t & 63;
    const int n = lane & 15, quad = lane >> 4;
    const int wr = w >> 2, wc = w & 3;               // wave -> 64x32 sub-tile

    // A-staging: thread t covers row row0+(t>>2), k-chunk (t&3)*8 (fp32 now)
    const int arow = row0 + (t >> 2);
    const float* pv  = values + (size_t)arow * DD + (t & 3) * 8;
    const float* pov = ovals  + (size_t)arow * DD + (t & 3) * 8;
    const int scbase = (arow >> 11) * (HH * LL) + (arow & 2047);  // + h*LL
    // B-staging (gload_lds direct, linear) -- fcwb now holds W2T bf16
    const unsigned short* gb = fcwb + (size_t)(col0 + (t >> 2)) * DD + (t & 3) * 8;
    unsigned short* la0 = &lds[0][0][t * 8];
    unsigned short* lb0 = &lds[0][1][t * 8];
    unsigned short* la1 = &lds[1][0][t * 8];
    unsigned short* lb1 = &lds[1][1][t * 8];
    const unsigned short* A0 = &lds[0][0][0];
    const unsigned short* B0 = &lds[0][1][0];
    const unsigned short* A1 = &lds[1][0][0];
    const unsigned short* B1 = &lds[1][1][0];

    f32x4 acc[4][2];
#pragma unroll
    for (int mt = 0; mt < 4; ++mt)
#pragma unroll
        for (int nt = 0; nt < 2; ++nt) acc[mt][nt] = (f32x4){0.f, 0.f, 0.f, 0.f};

    // prologue: A(0)->P, A(1)->Q, B(0)->lds0; write A(0)
    float4 vP0, vP1, oP0, oP1, vQ0, vQ1, oQ0, oQ1;
    float zP, eP, csP, zQ, eQ, csQ;
    LOADA(vP0, vP1, oP0, oP1, zP, eP, csP, 0);
    LOADA(vQ0, vQ1, oQ0, oQ1, zQ, eQ, csQ, 1);
    gload16(gb, lb0);
    CVTWRITE(vP0, vP1, oP0, oP1, zP, eP, csP, la0);
    __syncthreads();

    for (int kt = 0; kt < 32; kt += 2) {
        // even step: read lds0, prep lds1 with A(kt+1)/B(kt+1)
        gload16(gb + (kt + 1) * 32, lb1);
        if (kt + 2 < 32) LOADA(vP0, vP1, oP0, oP1, zP, eP, csP, kt + 2);
        COMPUTE(A0, B0);
        CVTWRITE(vQ0, vQ1, oQ0, oQ1, zQ, eQ, csQ, la1);
        __syncthreads();
        // odd step: read lds1, prep lds0 with A(kt+2)/B(kt+2)
        if (kt + 2 < 32) {
            gload16(gb + (kt + 2) * 32, lb0);
            if (kt + 3 < 32) LOADA(vQ0, vQ1, oQ0, oQ1, zQ, eQ, csQ, kt + 3);
        }
        COMPUTE(A1, B1);
        if (kt + 2 < 32) CVTWRITE(vP0, vP1, oP0, oP1, zP, eP, csP, la0);
        __syncthreads();
    }

#pragma unroll
    for (int nt = 0; nt < 2; ++nt) {
        const int col = col0 + wc * 32 + nt * 16 + n;
        const float bias = fc_b[col];
#pragma unroll
        for (int mt = 0; mt < 4; ++mt)
#pragma unroll
            for (int r = 0; r < 4; ++r)
                out[(size_t)(row0 + wr * 64 + mt * 16 + quad * 4 + r) * DD + col]
                    = acc[mt][nt][r] + bias;
    }
}

// ---------------------------------------------------------------------------
extern "C" void kernel_launch(void* const* d_in, const int* in_sizes, int n_in,
                              void* d_out, int out_size, void* d_ws, size_t ws_size,
                              hipStream_t stream) {
    const float* values = (const float*)d_in[0];
    const float* keys   = (const float*)d_in[1];
    const float* query  = (const float*)d_in[2];
    const float* ovals  = (const float*)d_in[3];
    const float* okeys  = (const float*)d_in[4];
    const float* Wv     = (const float*)d_in[5];
    const float* Wk     = (const float*)d_in[6];
    const float* Wq     = (const float*)d_in[7];
    const float* fc_w   = (const float*)d_in[8];
    const float* fc_b   = (const float*)d_in[9];
    // d_in[10]: mask — HIST==L makes it pure causal, handled analytically.
    float* out = (float*)d_out;

    float* ws      = (float*)d_ws;
    float* ediag   = ws;                     // 65536 f32
    float* Zbuf    = ediag + 65536;          // 65536 f32 (plain stores)
    float* colsum  = Zbuf + 65536;           // 65536 f32 (plain stores)
    unsigned short* qb   = (unsigned short*)(colsum + 65536); // [32][2048][64] bf16
    unsigned short* okb  = qb   + 4194304;
    unsigned short* fcwb = okb  + 4194304;   // W2T [1024][1024] bf16
    unsigned short* wfrag = fcwb + 1048576;  // M^T frags: 512*8 bf16 (8 KB)

    prepM_kernel<<<dim3(16), 256, 0, stream>>>(Wq, Wk, wfrag);
    proj_kernel<<<dim3(64, 16), 256, 0, stream>>>(
        query, keys, okeys, wfrag, qb, okb, ediag);
    prep2_kernel<<<dim3(1024), 256, 0, stream>>>(fc_w, Wv, fcwb);
    zrow_part<<<dim3(1024), 256, 0, stream>>>(qb, okb, Zbuf);
    colsum_part<<<dim3(1024), 256, 0, stream>>>(qb, okb, Zbuf, ediag, colsum);
    out_kernel<<<dim3(256), 512, 0, stream>>>(
        values, ovals, Zbuf, ediag, colsum, fcwb, fc_b, out);
}